// Round 7
// baseline (3041.765 us; speedup 1.0000x reference)
//
#include <hip/hip_runtime.h>

#define TLEN  1024
#define HID   96
#define NGATE 384
#define NTHR  768
#define WSTR  24   // floats per thread in LDS (phase-C cols 72..95)
#define WPAD  28   // row stride in floats: 112B, 16B-aligned, bank-permuted

__device__ __forceinline__ float sigf(float x) {
    return 1.0f / (1.0f + __expf(-x));
}
__device__ __forceinline__ float tanh_fast(float x) {
    float e = __expf(2.0f * x);
    return 1.0f - 2.0f / (e + 1.0f);
}

// Plain struct (scalar members) so each component is a clean asm lvalue.
struct AF4 { float x, y, z, w; };

// One-time: move a loaded float4 into AGPRs. asm-origin + "a"-class values
// are NOT rematerializable and CANNOT be silently re-loaded from global —
// the enforcement the allocator honored no hint for in rounds 1-5.
#define TO_A4(DST, SRC)                                              \
    asm volatile("v_accvgpr_write_b32 %0, %4\n\t"                    \
                 "v_accvgpr_write_b32 %1, %5\n\t"                    \
                 "v_accvgpr_write_b32 %2, %6\n\t"                    \
                 "v_accvgpr_write_b32 %3, %7"                        \
                 : "=a"((DST).x), "=a"((DST).y),                     \
                   "=a"((DST).z), "=a"((DST).w)                      \
                 : "v"((SRC).x), "v"((SRC).y),                       \
                   "v"((SRC).z), "v"((SRC).w))

// gfx950 VALU cannot source AGPRs directly (R6 compile fail) — explicit
// v_accvgpr_read into temps, then plain FMAs the scheduler can interleave.
// volatile: prevents CSE/LICM from hoisting 120 reads out of the loop.
#define QFMA_AR(W, HV, I)                                            \
    {                                                                \
        float4 h4 = (HV)[I];                                         \
        float wx, wy, wz, ww;                                        \
        asm volatile("v_accvgpr_read_b32 %0, %4\n\t"                 \
                     "v_accvgpr_read_b32 %1, %5\n\t"                 \
                     "v_accvgpr_read_b32 %2, %6\n\t"                 \
                     "v_accvgpr_read_b32 %3, %7"                     \
                     : "=v"(wx), "=v"(wy), "=v"(wz), "=v"(ww)        \
                     : "a"((W).x), "a"((W).y),                       \
                       "a"((W).z), "a"((W).w));                      \
        accx = fmaf(wx, h4.x, accx);                                 \
        accy = fmaf(wy, h4.y, accy);                                 \
        accz = fmaf(wz, h4.z, accz);                                 \
        accw = fmaf(ww, h4.w, accw);                                 \
    }

// LDS-tail FMA (weights stream from LDS, plain VALU)
#define QFMA_L(W, HV, I)                                 \
    {                                                    \
        float4 h4 = (HV)[I];                             \
        accx = fmaf((W).x, h4.x, accx);                  \
        accy = fmaf((W).y, h4.y, accy);                  \
        accz = fmaf((W).z, h4.z, accz);                  \
        accw = fmaf((W).w, h4.w, accw);                  \
    }

extern "C" __global__ void __launch_bounds__(NTHR)
__attribute__((amdgpu_waves_per_eu(3, 3)))
lstm2_fused(const float* __restrict__ x,
            const float* __restrict__ Wih0, const float* __restrict__ Whh0,
            const float* __restrict__ bih0, const float* __restrict__ bhh0,
            const float* __restrict__ Wih1, const float* __restrict__ Whh1,
            const float* __restrict__ bih1, const float* __restrict__ bhh1,
            const float* __restrict__ Wl,   const float* __restrict__ bl,
            float* __restrict__ out)
{
    // ~95 KB LDS: one 768-thread block per CU, occupancy capped at 3 waves/EU.
    __shared__ __attribute__((aligned(16))) float x_s[TLEN];
    __shared__ __attribute__((aligned(16))) float out_s[TLEN];
    __shared__ __attribute__((aligned(16))) float g_s[NGATE];
    __shared__ __attribute__((aligned(16))) float h1_s[HID];
    __shared__ __attribute__((aligned(16))) float h2_s[HID];
    __shared__ __attribute__((aligned(16))) float po_s[HID];
    __shared__ __attribute__((aligned(16))) float wlds[NTHR * WPAD];  // 84 KB

    const int tid  = threadIdx.x;
    const int b    = blockIdx.x;
    const int j    = tid >> 1;   // gate row 0..383 (torch order i,f,g,o)
    const int half = tid & 1;

    for (int i = tid; i < TLEN; i += NTHR) x_s[i] = x[b * TLEN + i];

    // ---- phase-A weights -> AGPRs: Whh0[j][48*half .. +47] ----
    AF4 wa0, wa1, wa2, wa3, wa4, wa5, wa6, wa7, wa8, wa9, wa10, wa11;
    {
        const float4* p0 = reinterpret_cast<const float4*>(Whh0 + j * HID + 48 * half);
        float4 t;
        t = p0[0];  TO_A4(wa0, t);   t = p0[1];  TO_A4(wa1, t);
        t = p0[2];  TO_A4(wa2, t);   t = p0[3];  TO_A4(wa3, t);
        t = p0[4];  TO_A4(wa4, t);   t = p0[5];  TO_A4(wa5, t);
        t = p0[6];  TO_A4(wa6, t);   t = p0[7];  TO_A4(wa7, t);
        t = p0[8];  TO_A4(wa8, t);   t = p0[9];  TO_A4(wa9, t);
        t = p0[10]; TO_A4(wa10, t);  t = p0[11]; TO_A4(wa11, t);
    }

    // ---- phase-C weights: cols 0..71 -> AGPRs; cols 72..95 -> LDS ----
    AF4 wb0, wb1, wb2, wb3, wb4, wb5, wb6, wb7, wb8;
    AF4 wb9, wb10, wb11, wb12, wb13, wb14, wb15, wb16, wb17;
    {
        const float* m1 = half ? Whh1 : Wih1;
        const float4* p1 = reinterpret_cast<const float4*>(m1 + j * HID);
        float4 t;
        t = p1[0];  TO_A4(wb0, t);   t = p1[1];  TO_A4(wb1, t);
        t = p1[2];  TO_A4(wb2, t);   t = p1[3];  TO_A4(wb3, t);
        t = p1[4];  TO_A4(wb4, t);   t = p1[5];  TO_A4(wb5, t);
        t = p1[6];  TO_A4(wb6, t);   t = p1[7];  TO_A4(wb7, t);
        t = p1[8];  TO_A4(wb8, t);   t = p1[9];  TO_A4(wb9, t);
        t = p1[10]; TO_A4(wb10, t);  t = p1[11]; TO_A4(wb11, t);
        t = p1[12]; TO_A4(wb12, t);  t = p1[13]; TO_A4(wb13, t);
        t = p1[14]; TO_A4(wb14, t);  t = p1[15]; TO_A4(wb15, t);
        t = p1[16]; TO_A4(wb16, t);  t = p1[17]; TO_A4(wb17, t);
        float4* wl = reinterpret_cast<float4*>(wlds + tid * WPAD);
        wl[0] = p1[18]; wl[1] = p1[19]; wl[2] = p1[20];
        wl[3] = p1[21]; wl[4] = p1[22]; wl[5] = p1[23];
    }

    const float bias0 = bih0[j] + bhh0[j];
    const float wx0   = Wih0[j];              // W_ih0 is [384,1]
    const float bias1 = bih1[j] + bhh1[j];
    const float wl_u  = (tid < HID) ? Wl[tid] : 0.0f;
    const float bl0   = bl[0];

    float c1 = 0.0f, c2 = 0.0f;
    if (tid < HID) { h1_s[tid] = 0.0f; h2_s[tid] = 0.0f; }
    __syncthreads();

    #pragma unroll 1
    for (int t = 0; t < TLEN; ++t) {
        // ---- A: g0[j] = bias0 + x_t*Wih0[j] + dot(Whh0[j], h1_prev) ----
        {
            const float4* hA = reinterpret_cast<const float4*>(h1_s + 48 * half);
            float accx = 0.f, accy = 0.f, accz = 0.f, accw = 0.f;
            QFMA_AR(wa0, hA, 0)  QFMA_AR(wa1, hA, 1)  QFMA_AR(wa2, hA, 2)
            QFMA_AR(wa3, hA, 3)  QFMA_AR(wa4, hA, 4)  QFMA_AR(wa5, hA, 5)
            QFMA_AR(wa6, hA, 6)  QFMA_AR(wa7, hA, 7)  QFMA_AR(wa8, hA, 8)
            QFMA_AR(wa9, hA, 9)  QFMA_AR(wa10, hA, 10) QFMA_AR(wa11, hA, 11)
            float s = (accx + accy) + (accz + accw);
            s += __shfl_xor(s, 1);
            if (half == 0) g_s[j] = s + bias0 + wx0 * x_s[t];
        }
        __syncthreads();
        // ---- B: layer-1 pointwise (96 units) ----
        if (tid < HID) {
            float gi = g_s[tid];
            float gf = g_s[HID + tid];
            float gg = g_s[2 * HID + tid];
            float go = g_s[3 * HID + tid];
            c1 = sigf(gf) * c1 + sigf(gi) * tanh_fast(gg);
            h1_s[tid] = sigf(go) * tanh_fast(c1);
        }
        __syncthreads();
        // ---- C: g1[j] = bias1 + dot(Wih1[j], h1_t) + dot(Whh1[j], h2_prev) ----
        {
            const float4* hC = reinterpret_cast<const float4*>(half ? h2_s : h1_s);
            float accx = 0.f, accy = 0.f, accz = 0.f, accw = 0.f;
            QFMA_AR(wb0, hC, 0)   QFMA_AR(wb1, hC, 1)   QFMA_AR(wb2, hC, 2)
            QFMA_AR(wb3, hC, 3)   QFMA_AR(wb4, hC, 4)   QFMA_AR(wb5, hC, 5)
            QFMA_AR(wb6, hC, 6)   QFMA_AR(wb7, hC, 7)   QFMA_AR(wb8, hC, 8)
            QFMA_AR(wb9, hC, 9)   QFMA_AR(wb10, hC, 10) QFMA_AR(wb11, hC, 11)
            QFMA_AR(wb12, hC, 12) QFMA_AR(wb13, hC, 13) QFMA_AR(wb14, hC, 14)
            QFMA_AR(wb15, hC, 15) QFMA_AR(wb16, hC, 16) QFMA_AR(wb17, hC, 17)
            // tail cols 72..95 from LDS; opaque zero defeats LICM hoisting
            int zr;
            asm volatile("v_mov_b32 %0, 0" : "=v"(zr));
            const float4* wl = reinterpret_cast<const float4*>(wlds + tid * WPAD + zr);
            QFMA_L(wl[0], hC, 18) QFMA_L(wl[1], hC, 19) QFMA_L(wl[2], hC, 20)
            QFMA_L(wl[3], hC, 21) QFMA_L(wl[4], hC, 22) QFMA_L(wl[5], hC, 23)
            float s = (accx + accy) + (accz + accw);
            s += __shfl_xor(s, 1);
            if (half == 0) g_s[j] = s + bias1;
        }
        __syncthreads();
        // ---- D: layer-2 pointwise + linear-head partials ----
        if (tid < HID) {
            float gi = g_s[tid];
            float gf = g_s[HID + tid];
            float gg = g_s[2 * HID + tid];
            float go = g_s[3 * HID + tid];
            c2 = sigf(gf) * c2 + sigf(gi) * tanh_fast(gg);
            float h2 = sigf(go) * tanh_fast(c2);
            h2_s[tid] = h2;
            po_s[tid] = wl_u * h2;
        }
        __syncthreads();
        // ---- E: out[b][t] = sum(po) + bl (wave 0; no trailing barrier needed) ----
        if (tid < 64) {
            float v = po_s[tid] + ((tid < 32) ? po_s[64 + tid] : 0.0f);
            v += __shfl_xor(v, 32);
            v += __shfl_xor(v, 16);
            v += __shfl_xor(v, 8);
            v += __shfl_xor(v, 4);
            v += __shfl_xor(v, 2);
            v += __shfl_xor(v, 1);
            if (tid == 0) out_s[t] = v + bl0;
        }
    }
    __syncthreads();
    for (int i = tid; i < TLEN; i += NTHR) out[b * TLEN + i] = out_s[i];
}

extern "C" void kernel_launch(void* const* d_in, const int* in_sizes, int n_in,
                              void* d_out, int out_size, void* d_ws, size_t ws_size,
                              hipStream_t stream)
{
    (void)in_sizes; (void)n_in; (void)d_ws; (void)ws_size; (void)out_size;
    const float* x    = (const float*)d_in[0];
    const float* Wih0 = (const float*)d_in[1];
    const float* Whh0 = (const float*)d_in[2];
    const float* bih0 = (const float*)d_in[3];
    const float* bhh0 = (const float*)d_in[4];
    const float* Wih1 = (const float*)d_in[5];
    const float* Whh1 = (const float*)d_in[6];
    const float* bih1 = (const float*)d_in[7];
    const float* bhh1 = (const float*)d_in[8];
    const float* Wl   = (const float*)d_in[9];
    const float* bl   = (const float*)d_in[10];

    lstm2_fused<<<dim3(256), dim3(NTHR), 0, stream>>>(
        x, Wih0, Whh0, bih0, bhh0, Wih1, Whh1, bih1, bhh1, Wl, bl,
        (float*)d_out);
}